// Round 1
// baseline (358.214 us; speedup 1.0000x reference)
//
#include <hip/hip_runtime.h>

#define EPS 1e-6f
#define LN2F 0.69314718055994530942f
#define ROWS_PER_BLOCK 4

struct RunStats { int len, pre, suf, mx; };

__device__ inline RunStats rcombine(const RunStats& a, const RunStats& b) {
    RunStats r;
    r.len = a.len + b.len;
    r.pre = (a.pre == a.len) ? (a.len + b.pre) : a.pre;
    r.suf = (b.suf == b.len) ? (b.len + a.suf) : b.suf;
    r.mx  = max(max(a.mx, b.mx), a.suf + b.pre);
    return r;
}

// 2048 blocks x 256 threads; each block owns 4 consecutive rows with a
// 1-row-deep register prefetch pipeline: row r+1's 12 float4 loads are issued
// (sched_barrier-pinned) BEFORE row r's compute + reduce, so the LDS-shuffle
// tail always has ~12KB/wave of memory in flight. The nibble transpose is
// wave-private -> no block barrier needed there; one __syncthreads per row
// with parity-double-buffered sstat/ssum for the cross-wave combine.
__global__ __launch_bounds__(256, 4) void row_kernel(
        const float* __restrict__ yp, const float* __restrict__ yt,
        const float* __restrict__ dw,
        float* __restrict__ blk_wbce, int* __restrict__ blk_streak) {
    const int lane = threadIdx.x & 63;
    const int wave = threadIdx.x >> 6;
    const int r0   = blockIdx.x * ROWS_PER_BLOCK;
    const long tofs = (long)wave * 1024 + lane * 4;

    __shared__ unsigned nibbuf[256];       // wave-private 64-dword segments
    __shared__ RunStats sstat[2][4];       // [row parity][wave]
    __shared__ float    ssum[2][4];

    float4 P[2][4], T[2][4], W[2][4];      // row double buffer (96 VGPRs)

    {   // prologue: issue row 0's 12 coalesced loads
        const float4* pp = (const float4*)(yp + (long)r0 * 4096 + tofs);
        const float4* tp = (const float4*)(yt + (long)r0 * 4096 + tofs);
        const float4* wp = (const float4*)(dw + (long)r0 * 4096 + tofs);
        #pragma unroll
        for (int q = 0; q < 4; ++q) {
            P[0][q] = pp[q * 64];          // +256 floats per chunk
            T[0][q] = tp[q * 64];
            W[0][q] = wp[q * 64];
        }
    }

    float acc_wbce   = 0.0f;               // only thread 0's copy is used
    int   acc_streak = 0;

    #pragma unroll
    for (int r = 0; r < ROWS_PER_BLOCK; ++r) {
        const int cur = r & 1;
        const int nxt = cur ^ 1;

        // ---- prefetch row r+1: stays in flight through compute + reduce ----
        if (r + 1 < ROWS_PER_BLOCK) {
            const float4* pp = (const float4*)(yp + (long)(r0 + r + 1) * 4096 + tofs);
            const float4* tp = (const float4*)(yt + (long)(r0 + r + 1) * 4096 + tofs);
            const float4* wp = (const float4*)(dw + (long)(r0 + r + 1) * 4096 + tofs);
            #pragma unroll
            for (int q = 0; q < 4; ++q) {
                P[nxt][q] = pp[q * 64];
                T[nxt][q] = tp[q * 64];
                W[nxt][q] = wp[q * 64];
            }
        }
        __builtin_amdgcn_sched_barrier(0); // pin prefetch issue above compute

        // ---- compute phase on row r's registers ----
        float sum = 0.0f;
        unsigned nibs = 0;
        #pragma unroll
        for (int q = 0; q < 4; ++q) {
            const float pv[4] = {P[cur][q].x, P[cur][q].y, P[cur][q].z, P[cur][q].w};
            const float tv[4] = {T[cur][q].x, T[cur][q].y, T[cur][q].z, T[cur][q].w};
            const float wv[4] = {W[cur][q].x, W[cur][q].y, W[cur][q].z, W[cur][q].w};
            #pragma unroll
            for (int c = 0; c < 4; ++c) {
                const bool tb = tv[c] != 0.0f;               // y_true is 0/1
                const float sel = tb ? pv[c] : 1.0f - pv[c];
                sum = fmaf(wv[c], __log2f(sel + EPS), sum);
                const bool correct = (pv[c] > 0.5f) == tb;
                nibs |= (unsigned)correct << (8 * q + c);
            }
        }

        // ---- wave-private LDS nibble transpose (no block barrier needed:
        // each wave reads only its own 64-dword segment; lgkmcnt orders it) ----
        nibbuf[wave * 64 + lane] = nibs;
        asm volatile("s_waitcnt lgkmcnt(0)" ::: "memory");
        const uint4 d = *(const uint4*)&nibbuf[wave * 64 + 4 * (lane & 15)];
        const int qs = (lane >> 4) * 8;                      // chunk-selecting byte shift
        const unsigned mask = ((d.x >> qs) & 0xFu)
                            | (((d.y >> qs) & 0xFu) << 4)
                            | (((d.z >> qs) & 0xFu) << 8)
                            | (((d.w >> qs) & 0xFu) << 12);

        // ---- per-lane run stats over the 16-bit mask (bit0 = first elem) ----
        const int pre = __builtin_ctz(~mask);                // 16 iff mask==0xffff
        const int suf = __builtin_clz(~(mask << 16));        // trailing-run via top bits
        int mx;
        {
            const unsigned p1 = mask;
            const unsigned p2 = p1 & (p1 << 1);
            const unsigned p4 = p2 & (p2 << 2);
            const unsigned p8 = p4 & (p4 << 4);
            unsigned z; int len;
            if (p8)      { z = p8; len = 8; }
            else if (p4) { z = p4; len = 4; }
            else if (p2) { z = p2; len = 2; }
            else         { z = p1; len = 1; }
            { const unsigned t = (z << 8) & p8; if (t) { z = t; len += 8; } }
            { const unsigned t = (z << 4) & p4; if (t) { z = t; len += 4; } }
            { const unsigned t = (z << 2) & p2; if (t) { z = t; len += 2; } }
            { const unsigned t = (z << 1) & p1; if (t) { z = t; len += 1; } }
            mx = mask ? len : 0;
        }

        // wbce wave sum (commutative butterfly)
        float wsum = sum;
        #pragma unroll
        for (int off = 32; off; off >>= 1) wsum += __shfl_down(wsum, off);

        // ordered wave reduce of (pre,suf,mx): 5 packed 10-bit steps, then a
        // final unpacked step (fields may reach 1024). Lane 0 valid.
        int packed = pre | (suf << 10) | (mx << 20);
        int alen = 16;
        #pragma unroll
        for (int off = 1; off < 32; off <<= 1) {
            const int o = __shfl_down(packed, off);
            const int apre = packed & 1023, asuf = (packed >> 10) & 1023, amx = packed >> 20;
            const int bpre = o & 1023,      bsuf = (o >> 10) & 1023,      bmx = o >> 20;
            const int npre = (apre == alen) ? (alen + bpre) : apre;
            const int nsuf = (bsuf == alen) ? (alen + asuf) : bsuf;
            const int nmx  = max(max(amx, bmx), asuf + bpre);
            packed = npre | (nsuf << 10) | (nmx << 20);
            alen <<= 1;
        }
        RunStats g;
        {   // final step: off = 32, alen = 512
            const int o = __shfl_down(packed, 32);
            const int apre = packed & 1023, asuf = (packed >> 10) & 1023, amx = packed >> 20;
            const int bpre = o & 1023,      bsuf = (o >> 10) & 1023,      bmx = o >> 20;
            g.len = 1024;
            g.pre = (apre == 512) ? (512 + bpre) : apre;
            g.suf = (bsuf == 512) ? (512 + asuf) : bsuf;
            g.mx  = max(max(amx, bmx), asuf + bpre);
        }

        if (lane == 0) { sstat[cur][wave] = g; ssum[cur][wave] = wsum; }
        __syncthreads();
        if (threadIdx.x == 0) {
            // reads of parity `cur` are separated from the next writes to the
            // same parity (row r+2) by barrier r+1 -> race-free.
            RunStats rr = rcombine(rcombine(sstat[cur][0], sstat[cur][1]),
                                   rcombine(sstat[cur][2], sstat[cur][3]));
            acc_wbce   += ssum[cur][0] + ssum[cur][1] + ssum[cur][2] + ssum[cur][3];
            acc_streak += rr.mx;
        }
    }

    if (threadIdx.x == 0) {
        blk_wbce[blockIdx.x]   = -LN2F * acc_wbce;
        blk_streak[blockIdx.x] = acc_streak;
    }
}

__global__ __launch_bounds__(1024) void finalize_kernel(
        const float* __restrict__ blk_wbce, const int* __restrict__ blk_streak,
        int nparts, long long total_elems, float* __restrict__ out) {
    double s = 0.0;
    long long st = 0;
    for (int i = threadIdx.x; i < nparts; i += 1024) {
        s  += (double)blk_wbce[i];
        st += (long long)blk_streak[i];
    }
    __shared__ double sd[1024];
    __shared__ long long sl[1024];
    sd[threadIdx.x] = s; sl[threadIdx.x] = st;
    __syncthreads();
    for (int o = 512; o; o >>= 1) {
        if (threadIdx.x < o) {
            sd[threadIdx.x] += sd[threadIdx.x + o];
            sl[threadIdx.x] += sl[threadIdx.x + o];
        }
        __syncthreads();
    }
    if (threadIdx.x == 0) {
        const double total = (double)total_elems;
        const double wbce = sd[0] / total;
        // mean over rows of (1 - streak/N) == 1 - sum_streak/(rows*N)
        const double cwl  = 1.0 - (double)sl[0] / total;
        out[0] = (float)(0.5 * wbce + 0.5 * cwl);
    }
}

extern "C" void kernel_launch(void* const* d_in, const int* in_sizes, int n_in,
                              void* d_out, int out_size, void* d_ws, size_t ws_size,
                              hipStream_t stream) {
    const float* yp = (const float*)d_in[0];
    const float* yt = (const float*)d_in[1];
    const float* dw = (const float*)d_in[2];
    float* out = (float*)d_out;

    const int rows    = in_sizes[0] / 4096;        // 8192
    const int nblocks = rows / ROWS_PER_BLOCK;     // 2048

    float* blk_wbce   = (float*)d_ws;
    int*   blk_streak = (int*)((char*)d_ws + (size_t)nblocks * sizeof(float));

    row_kernel<<<nblocks, 256, 0, stream>>>(yp, yt, dw, blk_wbce, blk_streak);
    finalize_kernel<<<1, 1024, 0, stream>>>(blk_wbce, blk_streak, nblocks,
                                            (long long)rows * 4096, out);
}